// Round 20
// baseline (421.394 us; speedup 1.0000x reference)
//
#include <hip/hip_runtime.h>
#include <hip/hip_bf16.h>

constexpr int MTOK = 1024;   // B*S
constexpr int HDIM = 2048;
constexpr int IDIM = 2048;
constexpr int NEXP = 16;
constexpr int TOPK = 4;
constexpr int NA   = MTOK * TOPK;   // 4096 assignments

#define ALPHA_C 1.702f
#define LIMIT_C 7.0f
#define RMS_EPS 1e-5f

using short8 = __attribute__((ext_vector_type(8))) short;
using f32x4  = __attribute__((ext_vector_type(4))) float;

__device__ __forceinline__ unsigned short f2bf(float f) {
    unsigned u = __builtin_bit_cast(unsigned, f);
    u += 0x7fffu + ((u >> 16) & 1u);     // round-to-nearest-even
    return (unsigned short)(u >> 16);
}

__device__ __forceinline__ unsigned pack2bf(float lo, float hi) {
    return (unsigned)f2bf(lo) | ((unsigned)f2bf(hi) << 16);
}

__device__ __forceinline__ short8 cvt8v(f32x4 a, f32x4 b) {
    union { short8 s; unsigned u[4]; } r;
    r.u[0] = pack2bf(a[0], a[1]);
    r.u[1] = pack2bf(a[2], a[3]);
    r.u[2] = pack2bf(b[0], b[1]);
    r.u[3] = pack2bf(b[2], b[3]);
    return r.s;
}

// ---------------- RMSNorm + router + top-k ----------------
__global__ __launch_bounds__(256) void k_router(
    const float* __restrict__ x, const float* __restrict__ norm_w,
    const float* __restrict__ gate_w, const float* __restrict__ gate_b,
    unsigned short* __restrict__ t_bf,
    int* __restrict__ counts, int* __restrict__ idx_of,
    int* __restrict__ slot_of, float* __restrict__ gate_mk)
{
    __shared__ float t_lds[HDIM];
    __shared__ float red[4];
    __shared__ float logits[NEXP];

    const int m   = blockIdx.x;
    const int tid = threadIdx.x;
    const float* xr = x + (size_t)m * HDIM;

    float4 v0 = ((const float4*)xr)[tid * 2];
    float4 v1 = ((const float4*)xr)[tid * 2 + 1];
    float ss = v0.x*v0.x + v0.y*v0.y + v0.z*v0.z + v0.w*v0.w
             + v1.x*v1.x + v1.y*v1.y + v1.z*v1.z + v1.w*v1.w;
    #pragma unroll
    for (int off = 32; off > 0; off >>= 1) ss += __shfl_down(ss, off);
    if ((tid & 63) == 0) red[tid >> 6] = ss;
    __syncthreads();
    float tot = red[0] + red[1] + red[2] + red[3];
    float scale = rsqrtf(tot / (float)HDIM + RMS_EPS);

    float4 n0 = ((const float4*)norm_w)[tid * 2];
    float4 n1 = ((const float4*)norm_w)[tid * 2 + 1];
    float t[8];
    t[0]=v0.x*scale*n0.x; t[1]=v0.y*scale*n0.y; t[2]=v0.z*scale*n0.z; t[3]=v0.w*scale*n0.w;
    t[4]=v1.x*scale*n1.x; t[5]=v1.y*scale*n1.y; t[6]=v1.z*scale*n1.z; t[7]=v1.w*scale*n1.w;
    short8 pk;
    #pragma unroll
    for (int j = 0; j < 8; ++j) {
        t_lds[tid * 8 + j] = t[j];
        pk[j] = (short)f2bf(t[j]);
    }
    *(short8*)(t_bf + (size_t)m * HDIM + tid * 8) = pk;
    __syncthreads();

    const int e = tid >> 4, j = tid & 15;
    const float4* gw4 = (const float4*)(gate_w + (size_t)e * HDIM);
    const float4* tl4 = (const float4*)t_lds;
    float part = 0.f;
    for (int h4 = j; h4 < HDIM / 4; h4 += 16) {
        float4 g = gw4[h4], tv = tl4[h4];
        part += g.x*tv.x + g.y*tv.y + g.z*tv.z + g.w*tv.w;
    }
    #pragma unroll
    for (int off = 8; off > 0; off >>= 1) part += __shfl_xor(part, off);
    if (j == 0) logits[e] = part + gate_b[e];
    __syncthreads();

    if (tid == 0) {
        float lv[NEXP];
        #pragma unroll
        for (int q = 0; q < NEXP; ++q) lv[q] = logits[q];
        int   sel[TOPK];
        float sv[TOPK];
        #pragma unroll
        for (int k = 0; k < TOPK; ++k) {
            float best = -1e30f; int bi = 0;
            for (int q = 0; q < NEXP; ++q)
                if (lv[q] > best) { best = lv[q]; bi = q; }
            sel[k] = bi; sv[k] = best; lv[bi] = -1e30f;
        }
        float mx = sv[0], s = 0.f, g[TOPK];
        #pragma unroll
        for (int k = 0; k < TOPK; ++k) { g[k] = __expf(sv[k] - mx); s += g[k]; }
        float inv = 1.f / s;
        #pragma unroll
        for (int k = 0; k < TOPK; ++k) {
            int a = m * TOPK + k;
            int slot = atomicAdd(&counts[sel[k]], 1);
            idx_of[a]  = sel[k];
            slot_of[a] = slot;
            gate_mk[a] = g[k] * inv;
        }
    }
}

// ---------------- scatter tokens into compact per-expert rows ----------------
__global__ void k_remap(const int* __restrict__ idx_of, const int* __restrict__ slot_of,
                        const int* __restrict__ counts,
                        int* __restrict__ token_of, int* __restrict__ rowidx)
{
    int a = blockIdx.x * blockDim.x + threadIdx.x;
    if (a >= NA) return;
    int e = idx_of[a];
    int off = 0;
    for (int q = 0; q < NEXP; ++q) off += (q < e) ? counts[q] : 0;
    int r = off + slot_of[a];
    token_of[r] = a >> 2;
    rowidx[a]   = r;
}

// ---------------- GEMM1 + bias + clamped SwiGLU -> act (bf16) ----------------
// 512 threads = 8 waves (4M x 2N). BM=320 x BN=128 (64 i-values), BK=32.
// Wave = 80 rows x 64 cols (acc[5][4]); a-cols wn*32+n*16, b-cols 64+wn*32+
// (n-2)*16 so SwiGLU pairs share a lane. XCD-expert pinning: xcd owns 2
// experts (A set 2MB <= L2). R10 issue-order pipeline: A(t+1), B(t+3),
// sched_barrier, publish B(t+1), setprio(1)+compute t+setprio(0);
// lgkmcnt-only barrier.
__global__ __launch_bounds__(512) void k_gemm1(
    const unsigned short* __restrict__ t_bf,
    const float* __restrict__ w1, const float* __restrict__ b1,
    const int* __restrict__ counts, const int* __restrict__ token_of,
    unsigned short* __restrict__ act)
{
    __shared__ unsigned char lB[2][10240];   // [buf][128 cols x 80B]

    const int bid = blockIdx.x;
    const int xcd = bid & 7;
    const int jj  = bid >> 3;               // 0..127
    const int e   = (xcd << 1) | (jj & 1);
    const int rem = jj >> 1;                // 0..63
    const int by  = rem >> 5;               // 0..1
    const int bx  = rem & 31;               // 0..31

    int ne = 0, roff = 0;
    #pragma unroll
    for (int q = 0; q < NEXP; ++q) {
        int cq = counts[q];
        roff += (q < e) ? cq : 0;
        ne    = (q == e) ? cq : ne;
    }
    const int brow = by * 320;
    if (brow >= ne) return;
    const int i0 = bx * 64;
    const int tid = threadIdx.x;

    const int wv = tid >> 6, ln = tid & 63;
    const int wm = wv >> 1, wn = wv & 1;
    const int lr = ln & 15, lk = ln >> 4;
    const int col = tid >> 2, bp = tid & 3;   // B staging: col 0..127, 8-float chunk

    const unsigned short* aptr[5];
    #pragma unroll
    for (int mf = 0; mf < 5; ++mf) {
        int rg = brow + wm * 80 + mf * 16 + lr;
        int tok = token_of[roff + (rg < ne ? rg : 0)];
        aptr[mf] = t_bf + (size_t)tok * HDIM + lk * 8;
    }
    const int o = (col < 64) ? (2 * (i0 + col)) : (2 * (i0 + col - 64) + 1);
    const float* bsrc = w1 + ((size_t)e * (2 * IDIM) + o) * HDIM + bp * 8;

    // fragment cols: n<2 -> a-half, n>=2 -> matching b-half
    int cfrag[4];
    cfrag[0] = wn * 32;      cfrag[1] = wn * 32 + 16;
    cfrag[2] = 64 + wn * 32; cfrag[3] = 64 + wn * 32 + 16;

    short8 aE[5], aO[5];
    f32x4 bS0[2], bS1[2], bS2[2], bS3[2];
    f32x4  acc[5][4] = {};

    constexpr int NT = 64;   // HDIM / 32

    #pragma unroll
    for (int mf = 0; mf < 5; ++mf) aE[mf] = *(const short8*)(aptr[mf]);
    {
        f32x4 p0 = *(const f32x4*)(bsrc);
        f32x4 p1 = *(const f32x4*)(bsrc + 4);
        *(short8*)(&lB[0][col * 80 + bp * 16]) = cvt8v(p0, p1);
    }
    bS1[0] = *(const f32x4*)(bsrc + 32);  bS1[1] = *(const f32x4*)(bsrc + 36);
    bS2[0] = *(const f32x4*)(bsrc + 64);  bS2[1] = *(const f32x4*)(bsrc + 68);
    asm volatile("s_waitcnt lgkmcnt(0)" ::: "memory");
    __builtin_amdgcn_s_barrier();

#define GSTEP(T_, AU, AP, SPUB, SISS)                                                    \
    {                                                                                    \
        const int t_ = (T_);                                                             \
        if (t_ + 1 < NT) {                                                               \
            _Pragma("unroll")                                                            \
            for (int mf = 0; mf < 5; ++mf)                                               \
                AP[mf] = *(const short8*)(aptr[mf] + (t_ + 1) * 32);                     \
        }                                                                                \
        if (t_ + 3 < NT) {                                                               \
            SISS[0] = *(const f32x4*)(bsrc + (t_ + 3) * 32);                             \
            SISS[1] = *(const f32x4*)(bsrc + (t_ + 3) * 32 + 4);                         \
        }                                                                                \
        __builtin_amdgcn_sched_barrier(0);                                               \
        if (t_ + 1 < NT)                                                                 \
            *(short8*)(&lB[(t_ + 1) & 1][col * 80 + bp * 16]) = cvt8v(SPUB[0], SPUB[1]); \
        short8 bfr[4];                                                                   \
        _Pragma("unroll")                                                                \
        for (int n = 0; n < 4; ++n)                                                      \
            bfr[n] = *(const short8*)(&lB[t_ & 1][(cfrag[n] + lr) * 80 + lk * 16]);      \
        __builtin_amdgcn_s_setprio(1);                                                   \
        _Pragma("unroll")                                                                \
        for (int mf = 0; mf < 5; ++mf)                                                   \
            _Pragma("unroll")                                                            \
            for (int n = 0; n < 4; ++n)                                                  \
                acc[mf][n] = __builtin_amdgcn_mfma_f32_16x16x32_bf16(                    \
                    AU[mf], bfr[n], acc[mf][n], 0, 0, 0);                                \
        __builtin_amdgcn_s_setprio(0);                                                   \
        asm volatile("s_waitcnt lgkmcnt(0)" ::: "memory");                               \
        __builtin_amdgcn_s_barrier();                                                    \
    }

    for (int t4 = 0; t4 < NT / 4; ++t4) {
        const int tb = t4 * 4;
        GSTEP(tb + 0, aE, aO, bS1, bS3)
        GSTEP(tb + 1, aO, aE, bS2, bS0)
        GSTEP(tb + 2, aE, aO, bS3, bS1)
        GSTEP(tb + 3, aO, aE, bS0, bS2)
    }
#undef GSTEP

    #pragma unroll
    for (int n = 0; n < 2; ++n) {
        const int i = i0 + wn * 32 + n * 16 + lr;
        const float ba = b1[(size_t)e * (2 * IDIM) + 2 * i];
        const float bb = b1[(size_t)e * (2 * IDIM) + 2 * i + 1];
        #pragma unroll
        for (int mf = 0; mf < 5; ++mf) {
            #pragma unroll
            for (int r = 0; r < 4; ++r) {
                const int rg = brow + wm * 80 + mf * 16 + lk * 4 + r;
                if (rg < ne) {
                    float ha = acc[mf][n][r] + ba;
                    float hb = acc[mf][n + 2][r] + bb;
                    float a = fminf(ha, LIMIT_C);
                    float b = fminf(fmaxf(hb, -LIMIT_C), LIMIT_C);
                    float s = 1.f / (1.f + __expf(-ALPHA_C * a));
                    act[(size_t)(roff + rg) * IDIM + i] = f2bf(a * s * (b + 1.f));
                }
            }
        }
    }
}

// ---------------- GEMM2 + bias -> ybuf half (bf16, un-gated) ----------------
// Same 8-wave structure, BN=128 d-cols, split-K=2 (ks), bias on ks==0.
__global__ __launch_bounds__(512) void k_gemm2(
    const unsigned short* __restrict__ act,
    const float* __restrict__ w2, const float* __restrict__ b2,
    const int* __restrict__ counts, const int* __restrict__ token_of,
    unsigned short* __restrict__ ybufA, unsigned short* __restrict__ ybufB)
{
    __shared__ unsigned char lB[2][10240];

    const int bid = blockIdx.x;
    const int xcd = bid & 7;
    const int jj  = bid >> 3;               // 0..127
    const int e   = (xcd << 1) | (jj & 1);
    const int rem = jj >> 1;                // 0..63
    const int by  = rem >> 5;               // 0..1
    const int r2  = rem & 31;
    const int ks  = r2 >> 4;                // 0..1
    const int bx  = r2 & 15;                // 0..15

    int ne = 0, roff = 0;
    #pragma unroll
    for (int q = 0; q < NEXP; ++q) {
        int cq = counts[q];
        roff += (q < e) ? cq : 0;
        ne    = (q == e) ? cq : ne;
    }
    const int brow = by * 320;
    if (brow >= ne) return;
    const int d0 = bx * 128;
    const int kbeg = ks * (IDIM / 2);
    const int tid = threadIdx.x;

    const int wv = tid >> 6, ln = tid & 63;
    const int wm = wv >> 1, wn = wv & 1;
    const int lr = ln & 15, lk = ln >> 4;
    const int col = tid >> 2, bp = tid & 3;

    const unsigned short* aptr[5];
    #pragma unroll
    for (int mf = 0; mf < 5; ++mf) {
        int rg = brow + wm * 80 + mf * 16 + lr;
        int rc = (rg < ne) ? rg : 0;
        aptr[mf] = act + (size_t)(roff + rc) * IDIM + kbeg + lk * 8;
    }
    const float* bsrc = w2 + ((size_t)e * HDIM + d0 + col) * IDIM + kbeg + bp * 8;

    int cfrag[4];
    cfrag[0] = wn * 64;      cfrag[1] = wn * 64 + 16;
    cfrag[2] = wn * 64 + 32; cfrag[3] = wn * 64 + 48;

    short8 aE[5], aO[5];
    f32x4 bS0[2], bS1[2], bS2[2], bS3[2];
    f32x4  acc[5][4] = {};

    constexpr int NT = 32;   // (IDIM/2) / 32

    #pragma unroll
    for (int mf = 0; mf < 5; ++mf) aE[mf] = *(const short8*)(aptr[mf]);
    {
        f32x4 p0 = *(const f32x4*)(bsrc);
        f32x4 p1 = *(const f32x4*)(bsrc + 4);
        *(short8*)(&lB[0][col * 80 + bp * 16]) = cvt8v(p0, p1);
    }
    bS1[0] = *(const f32x4*)(bsrc + 32);  bS1[1] = *(const f32x4*)(bsrc + 36);
    bS2[0] = *(const f32x4*)(bsrc + 64);  bS2[1] = *(const f32x4*)(bsrc + 68);
    asm volatile("s_waitcnt lgkmcnt(0)" ::: "memory");
    __builtin_amdgcn_s_barrier();

#define GSTEP(T_, AU, AP, SPUB, SISS)                                                    \
    {                                                                                    \
        const int t_ = (T_);                                                             \
        if (t_ + 1 < NT) {                                                               \
            _Pragma("unroll")                                                            \
            for (int mf = 0; mf < 5; ++mf)                                               \
                AP[mf] = *(const short8*)(aptr[mf] + (t_ + 1) * 32);                     \
        }                                                                                \
        if (t_ + 3 < NT) {                                                               \
            SISS[0] = *(const f32x4*)(bsrc + (t_ + 3) * 32);                             \
            SISS[1] = *(const f32x4*)(bsrc + (t_ + 3) * 32 + 4);                         \
        }                                                                                \
        __builtin_amdgcn_sched_barrier(0);                                               \
        if (t_ + 1 < NT)                                                                 \
            *(short8*)(&lB[(t_ + 1) & 1][col * 80 + bp * 16]) = cvt8v(SPUB[0], SPUB[1]); \
        short8 bfr[4];                                                                   \
        _Pragma("unroll")                                                                \
        for (int n = 0; n < 4; ++n)                                                      \
            bfr[n] = *(const short8*)(&lB[t_ & 1][(cfrag[n] + lr) * 80 + lk * 16]);      \
        __builtin_amdgcn_s_setprio(1);                                                   \
        _Pragma("unroll")                                                                \
        for (int mf = 0; mf < 5; ++mf)                                                   \
            _Pragma("unroll")                                                            \
            for (int n = 0; n < 4; ++n)                                                  \
                acc[mf][n] = __builtin_amdgcn_mfma_f32_16x16x32_bf16(                    \
                    AU[mf], bfr[n], acc[mf][n], 0, 0, 0);                                \
        __builtin_amdgcn_s_setprio(0);                                                   \
        asm volatile("s_waitcnt lgkmcnt(0)" ::: "memory");                               \
        __builtin_amdgcn_s_barrier();                                                    \
    }

    for (int t4 = 0; t4 < NT / 4; ++t4) {
        const int tb = t4 * 4;
        GSTEP(tb + 0, aE, aO, bS1, bS3)
        GSTEP(tb + 1, aO, aE, bS2, bS0)
        GSTEP(tb + 2, aE, aO, bS3, bS1)
        GSTEP(tb + 3, aO, aE, bS0, bS2)
    }
#undef GSTEP

    unsigned short* yb = ks ? ybufB : ybufA;
    #pragma unroll
    for (int mf = 0; mf < 5; ++mf) {
        #pragma unroll
        for (int r = 0; r < 4; ++r) {
            const int rg = brow + wm * 80 + mf * 16 + lk * 4 + r;
            if (rg >= ne) continue;
            unsigned short* yrow = yb + (size_t)(roff + rg) * HDIM;
            #pragma unroll
            for (int n = 0; n < 4; ++n) {
                const int d = d0 + cfrag[n] + lr;
                float v = acc[mf][n][r];
                if (ks == 0) v += b2[(size_t)e * HDIM + d];
                yrow[d] = f2bf(v);
            }
        }
    }
}

// ---------------- combine: out = x + sum_k gate_k * (ybufA+ybufB)[row_k] ----------------
__global__ __launch_bounds__(256) void k_comb(
    const float* __restrict__ x,
    const unsigned short* __restrict__ ybufA, const unsigned short* __restrict__ ybufB,
    const int* __restrict__ rowidx, const float* __restrict__ gate_mk,
    float* __restrict__ out)
{
    __shared__ int   rws[TOPK];
    __shared__ float gws[TOPK];
    const int m = blockIdx.x;
    const int tid = threadIdx.x;
    if (tid < TOPK) {
        rws[tid] = rowidx[m * TOPK + tid];
        gws[tid] = gate_mk[m * TOPK + tid];
    }
    __syncthreads();
    const int d = tid * 8;
    float4 o0 = ((const float4*)(x + (size_t)m * HDIM + d))[0];
    float4 o1 = ((const float4*)(x + (size_t)m * HDIM + d))[1];
    #pragma unroll
    for (int k = 0; k < TOPK; ++k) {
        const float g = gws[k];
        short8 ya = *(const short8*)(ybufA + (size_t)rws[k] * HDIM + d);
        short8 yb = *(const short8*)(ybufB + (size_t)rws[k] * HDIM + d);
        float yv[8];
        #pragma unroll
        for (int j = 0; j < 8; ++j) {
            unsigned ua = ((unsigned)(unsigned short)ya[j]) << 16;
            unsigned ub = ((unsigned)(unsigned short)yb[j]) << 16;
            yv[j] = __builtin_bit_cast(float, ua) + __builtin_bit_cast(float, ub);
        }
        o0.x += g * yv[0]; o0.y += g * yv[1]; o0.z += g * yv[2]; o0.w += g * yv[3];
        o1.x += g * yv[4]; o1.y += g * yv[5]; o1.z += g * yv[6]; o1.w += g * yv[7];
    }
    ((float4*)(out + (size_t)m * HDIM + d))[0] = o0;
    ((float4*)(out + (size_t)m * HDIM + d))[1] = o1;
}

extern "C" void kernel_launch(void* const* d_in, const int* in_sizes, int n_in,
                              void* d_out, int out_size, void* d_ws, size_t ws_size,
                              hipStream_t stream) {
    const float* x      = (const float*)d_in[0];
    const float* norm_w = (const float*)d_in[1];
    const float* gate_w = (const float*)d_in[2];
    const float* gate_b = (const float*)d_in[3];
    const float* w1     = (const float*)d_in[4];
    const float* b1     = (const float*)d_in[5];
    const float* w2     = (const float*)d_in[6];
    const float* b2     = (const float*)d_in[7];
    float* out = (float*)d_out;

    char* ws = (char*)d_ws;
    size_t off = 0;
    unsigned short* t_bf  = (unsigned short*)(ws + off); off += (size_t)MTOK * HDIM * 2;  // 4 MB
    unsigned short* actb  = (unsigned short*)(ws + off); off += (size_t)NA * IDIM * 2;    // 16.8 MB
    unsigned short* ybufA = (unsigned short*)(ws + off); off += (size_t)NA * HDIM * 2;    // 16.8 MB
    unsigned short* ybufB = (unsigned short*)(ws + off); off += (size_t)NA * HDIM * 2;    // 16.8 MB
    int*   counts   = (int*)(ws + off);   off += 256;
    int*   idx_of   = (int*)(ws + off);   off += (size_t)NA * 4;
    int*   slot_of  = (int*)(ws + off);   off += (size_t)NA * 4;
    float* gate_mk  = (float*)(ws + off); off += (size_t)NA * 4;
    int*   token_of = (int*)(ws + off);   off += (size_t)NA * 4;
    int*   rowidx   = (int*)(ws + off);   off += (size_t)NA * 4;

    (void)hipMemsetAsync(counts, 0, 256, stream);
    k_router<<<MTOK, 256, 0, stream>>>(x, norm_w, gate_w, gate_b, t_bf,
                                       counts, idx_of, slot_of, gate_mk);
    k_remap<<<NA / 256, 256, 0, stream>>>(idx_of, slot_of, counts,
                                          token_of, rowidx);
    // 1D grids, XCD-expert pinning: xcd = bid & 7 owns experts {2*xcd, 2*xcd+1}
    k_gemm1<<<1024, 512, 0, stream>>>(t_bf, w1, b1, counts, token_of, actb);
    k_gemm2<<<1024, 512, 0, stream>>>(actb, w2, b2, counts, token_of, ybufA, ybufB);
    k_comb<<<MTOK, 256, 0, stream>>>(x, ybufA, ybufB, rowidx, gate_mk, out);
}

// Round 21
// 396.585 us; speedup vs baseline: 1.0626x; 1.0626x over previous
//
#include <hip/hip_runtime.h>
#include <hip/hip_bf16.h>

constexpr int MTOK = 1024;   // B*S
constexpr int HDIM = 2048;
constexpr int IDIM = 2048;
constexpr int NEXP = 16;
constexpr int TOPK = 4;
constexpr int NA   = MTOK * TOPK;   // 4096 assignments

#define ALPHA_C 1.702f
#define LIMIT_C 7.0f
#define RMS_EPS 1e-5f

using short8 = __attribute__((ext_vector_type(8))) short;
using f32x4  = __attribute__((ext_vector_type(4))) float;

__device__ __forceinline__ unsigned short f2bf(float f) {
    unsigned u = __builtin_bit_cast(unsigned, f);
    u += 0x7fffu + ((u >> 16) & 1u);     // round-to-nearest-even
    return (unsigned short)(u >> 16);
}

__device__ __forceinline__ unsigned pack2bf(float lo, float hi) {
    return (unsigned)f2bf(lo) | ((unsigned)f2bf(hi) << 16);
}

__device__ __forceinline__ short8 cvt8v(f32x4 a, f32x4 b) {
    union { short8 s; unsigned u[4]; } r;
    r.u[0] = pack2bf(a[0], a[1]);
    r.u[1] = pack2bf(a[2], a[3]);
    r.u[2] = pack2bf(b[0], b[1]);
    r.u[3] = pack2bf(b[2], b[3]);
    return r.s;
}

// ---------------- RMSNorm + router + top-k ----------------
__global__ __launch_bounds__(256) void k_router(
    const float* __restrict__ x, const float* __restrict__ norm_w,
    const float* __restrict__ gate_w, const float* __restrict__ gate_b,
    unsigned short* __restrict__ t_bf,
    int* __restrict__ counts, int* __restrict__ idx_of,
    int* __restrict__ slot_of, float* __restrict__ gate_mk)
{
    __shared__ float t_lds[HDIM];
    __shared__ float red[4];
    __shared__ float logits[NEXP];

    const int m   = blockIdx.x;
    const int tid = threadIdx.x;
    const float* xr = x + (size_t)m * HDIM;

    float4 v0 = ((const float4*)xr)[tid * 2];
    float4 v1 = ((const float4*)xr)[tid * 2 + 1];
    float ss = v0.x*v0.x + v0.y*v0.y + v0.z*v0.z + v0.w*v0.w
             + v1.x*v1.x + v1.y*v1.y + v1.z*v1.z + v1.w*v1.w;
    #pragma unroll
    for (int off = 32; off > 0; off >>= 1) ss += __shfl_down(ss, off);
    if ((tid & 63) == 0) red[tid >> 6] = ss;
    __syncthreads();
    float tot = red[0] + red[1] + red[2] + red[3];
    float scale = rsqrtf(tot / (float)HDIM + RMS_EPS);

    float4 n0 = ((const float4*)norm_w)[tid * 2];
    float4 n1 = ((const float4*)norm_w)[tid * 2 + 1];
    float t[8];
    t[0]=v0.x*scale*n0.x; t[1]=v0.y*scale*n0.y; t[2]=v0.z*scale*n0.z; t[3]=v0.w*scale*n0.w;
    t[4]=v1.x*scale*n1.x; t[5]=v1.y*scale*n1.y; t[6]=v1.z*scale*n1.z; t[7]=v1.w*scale*n1.w;
    short8 pk;
    #pragma unroll
    for (int j = 0; j < 8; ++j) {
        t_lds[tid * 8 + j] = t[j];
        pk[j] = (short)f2bf(t[j]);
    }
    *(short8*)(t_bf + (size_t)m * HDIM + tid * 8) = pk;
    __syncthreads();

    const int e = tid >> 4, j = tid & 15;
    const float4* gw4 = (const float4*)(gate_w + (size_t)e * HDIM);
    const float4* tl4 = (const float4*)t_lds;
    float part = 0.f;
    for (int h4 = j; h4 < HDIM / 4; h4 += 16) {
        float4 g = gw4[h4], tv = tl4[h4];
        part += g.x*tv.x + g.y*tv.y + g.z*tv.z + g.w*tv.w;
    }
    #pragma unroll
    for (int off = 8; off > 0; off >>= 1) part += __shfl_xor(part, off);
    if (j == 0) logits[e] = part + gate_b[e];
    __syncthreads();

    if (tid == 0) {
        float lv[NEXP];
        #pragma unroll
        for (int q = 0; q < NEXP; ++q) lv[q] = logits[q];
        int   sel[TOPK];
        float sv[TOPK];
        #pragma unroll
        for (int k = 0; k < TOPK; ++k) {
            float best = -1e30f; int bi = 0;
            for (int q = 0; q < NEXP; ++q)
                if (lv[q] > best) { best = lv[q]; bi = q; }
            sel[k] = bi; sv[k] = best; lv[bi] = -1e30f;
        }
        float mx = sv[0], s = 0.f, g[TOPK];
        #pragma unroll
        for (int k = 0; k < TOPK; ++k) { g[k] = __expf(sv[k] - mx); s += g[k]; }
        float inv = 1.f / s;
        #pragma unroll
        for (int k = 0; k < TOPK; ++k) {
            int a = m * TOPK + k;
            int slot = atomicAdd(&counts[sel[k]], 1);
            idx_of[a]  = sel[k];
            slot_of[a] = slot;
            gate_mk[a] = g[k] * inv;
        }
    }
}

// ---------------- scatter tokens into compact per-expert rows ----------------
__global__ void k_remap(const int* __restrict__ idx_of, const int* __restrict__ slot_of,
                        const int* __restrict__ counts,
                        int* __restrict__ token_of, int* __restrict__ rowidx)
{
    int a = blockIdx.x * blockDim.x + threadIdx.x;
    if (a >= NA) return;
    int e = idx_of[a];
    int off = 0;
    for (int q = 0; q < NEXP; ++q) off += (q < e) ? counts[q] : 0;
    int r = off + slot_of[a];
    token_of[r] = a >> 2;
    rowidx[a]   = r;
}

// ---------------- GEMM1 + bias + clamped SwiGLU -> act (bf16) ----------------
// 512 threads = 8 waves (4M x 2N). BM=320 x BN=128 (64 i-values), BK=32.
// Wave = 80 rows x 64 cols (acc[5][4]); a-cols wn*32+n*16, b-cols 64+wn*32+
// (n-2)*16 so SwiGLU pairs share a lane. XCD-expert pinning: xcd owns 2
// experts (A set 2MB <= L2). R10 issue-order pipeline: A(t+1), B(t+3),
// sched_barrier, publish B(t+1), compute t; lgkmcnt-only barrier.
__global__ __launch_bounds__(512) void k_gemm1(
    const unsigned short* __restrict__ t_bf,
    const float* __restrict__ w1, const float* __restrict__ b1,
    const int* __restrict__ counts, const int* __restrict__ token_of,
    unsigned short* __restrict__ act)
{
    __shared__ unsigned char lB[2][10240];   // [buf][128 cols x 80B]

    const int bid = blockIdx.x;
    const int xcd = bid & 7;
    const int jj  = bid >> 3;               // 0..127
    const int e   = (xcd << 1) | (jj & 1);
    const int rem = jj >> 1;                // 0..63
    const int by  = rem >> 5;               // 0..1
    const int bx  = rem & 31;               // 0..31

    int ne = 0, roff = 0;
    #pragma unroll
    for (int q = 0; q < NEXP; ++q) {
        int cq = counts[q];
        roff += (q < e) ? cq : 0;
        ne    = (q == e) ? cq : ne;
    }
    const int brow = by * 320;
    if (brow >= ne) return;
    const int i0 = bx * 64;
    const int tid = threadIdx.x;

    const int wv = tid >> 6, ln = tid & 63;
    const int wm = wv >> 1, wn = wv & 1;
    const int lr = ln & 15, lk = ln >> 4;
    const int col = tid >> 2, bp = tid & 3;   // B staging: col 0..127, 8-float chunk

    const unsigned short* aptr[5];
    #pragma unroll
    for (int mf = 0; mf < 5; ++mf) {
        int rg = brow + wm * 80 + mf * 16 + lr;
        int tok = token_of[roff + (rg < ne ? rg : 0)];
        aptr[mf] = t_bf + (size_t)tok * HDIM + lk * 8;
    }
    const int o = (col < 64) ? (2 * (i0 + col)) : (2 * (i0 + col - 64) + 1);
    const float* bsrc = w1 + ((size_t)e * (2 * IDIM) + o) * HDIM + bp * 8;

    // fragment cols: n<2 -> a-half, n>=2 -> matching b-half
    int cfrag[4];
    cfrag[0] = wn * 32;      cfrag[1] = wn * 32 + 16;
    cfrag[2] = 64 + wn * 32; cfrag[3] = 64 + wn * 32 + 16;

    short8 aE[5], aO[5];
    f32x4 bS0[2], bS1[2], bS2[2], bS3[2];
    f32x4  acc[5][4] = {};

    constexpr int NT = 64;   // HDIM / 32

    #pragma unroll
    for (int mf = 0; mf < 5; ++mf) aE[mf] = *(const short8*)(aptr[mf]);
    {
        f32x4 p0 = *(const f32x4*)(bsrc);
        f32x4 p1 = *(const f32x4*)(bsrc + 4);
        *(short8*)(&lB[0][col * 80 + bp * 16]) = cvt8v(p0, p1);
    }
    bS1[0] = *(const f32x4*)(bsrc + 32);  bS1[1] = *(const f32x4*)(bsrc + 36);
    bS2[0] = *(const f32x4*)(bsrc + 64);  bS2[1] = *(const f32x4*)(bsrc + 68);
    asm volatile("s_waitcnt lgkmcnt(0)" ::: "memory");
    __builtin_amdgcn_s_barrier();

#define GSTEP(T_, AU, AP, SPUB, SISS)                                                    \
    {                                                                                    \
        const int t_ = (T_);                                                             \
        if (t_ + 1 < NT) {                                                               \
            _Pragma("unroll")                                                            \
            for (int mf = 0; mf < 5; ++mf)                                               \
                AP[mf] = *(const short8*)(aptr[mf] + (t_ + 1) * 32);                     \
        }                                                                                \
        if (t_ + 3 < NT) {                                                               \
            SISS[0] = *(const f32x4*)(bsrc + (t_ + 3) * 32);                             \
            SISS[1] = *(const f32x4*)(bsrc + (t_ + 3) * 32 + 4);                         \
        }                                                                                \
        __builtin_amdgcn_sched_barrier(0);                                               \
        if (t_ + 1 < NT)                                                                 \
            *(short8*)(&lB[(t_ + 1) & 1][col * 80 + bp * 16]) = cvt8v(SPUB[0], SPUB[1]); \
        short8 bfr[4];                                                                   \
        _Pragma("unroll")                                                                \
        for (int n = 0; n < 4; ++n)                                                      \
            bfr[n] = *(const short8*)(&lB[t_ & 1][(cfrag[n] + lr) * 80 + lk * 16]);      \
        _Pragma("unroll")                                                                \
        for (int mf = 0; mf < 5; ++mf)                                                   \
            _Pragma("unroll")                                                            \
            for (int n = 0; n < 4; ++n)                                                  \
                acc[mf][n] = __builtin_amdgcn_mfma_f32_16x16x32_bf16(                    \
                    AU[mf], bfr[n], acc[mf][n], 0, 0, 0);                                \
        asm volatile("s_waitcnt lgkmcnt(0)" ::: "memory");                               \
        __builtin_amdgcn_s_barrier();                                                    \
    }

    for (int t4 = 0; t4 < NT / 4; ++t4) {
        const int tb = t4 * 4;
        GSTEP(tb + 0, aE, aO, bS1, bS3)
        GSTEP(tb + 1, aO, aE, bS2, bS0)
        GSTEP(tb + 2, aE, aO, bS3, bS1)
        GSTEP(tb + 3, aO, aE, bS0, bS2)
    }
#undef GSTEP

    #pragma unroll
    for (int n = 0; n < 2; ++n) {
        const int i = i0 + wn * 32 + n * 16 + lr;
        const float ba = b1[(size_t)e * (2 * IDIM) + 2 * i];
        const float bb = b1[(size_t)e * (2 * IDIM) + 2 * i + 1];
        #pragma unroll
        for (int mf = 0; mf < 5; ++mf) {
            #pragma unroll
            for (int r = 0; r < 4; ++r) {
                const int rg = brow + wm * 80 + mf * 16 + lk * 4 + r;
                if (rg < ne) {
                    float ha = acc[mf][n][r] + ba;
                    float hb = acc[mf][n + 2][r] + bb;
                    float a = fminf(ha, LIMIT_C);
                    float b = fminf(fmaxf(hb, -LIMIT_C), LIMIT_C);
                    float s = 1.f / (1.f + __expf(-ALPHA_C * a));
                    act[(size_t)(roff + rg) * IDIM + i] = f2bf(a * s * (b + 1.f));
                }
            }
        }
    }
}

// ---------------- GEMM2 + bias -> ybuf half (bf16, un-gated) ----------------
// Same 8-wave structure, BN=128 d-cols, split-K=2 (ks), bias on ks==0.
__global__ __launch_bounds__(512) void k_gemm2(
    const unsigned short* __restrict__ act,
    const float* __restrict__ w2, const float* __restrict__ b2,
    const int* __restrict__ counts, const int* __restrict__ token_of,
    unsigned short* __restrict__ ybufA, unsigned short* __restrict__ ybufB)
{
    __shared__ unsigned char lB[2][10240];

    const int bid = blockIdx.x;
    const int xcd = bid & 7;
    const int jj  = bid >> 3;               // 0..127
    const int e   = (xcd << 1) | (jj & 1);
    const int rem = jj >> 1;                // 0..63
    const int by  = rem >> 5;               // 0..1
    const int r2  = rem & 31;
    const int ks  = r2 >> 4;                // 0..1
    const int bx  = r2 & 15;                // 0..15

    int ne = 0, roff = 0;
    #pragma unroll
    for (int q = 0; q < NEXP; ++q) {
        int cq = counts[q];
        roff += (q < e) ? cq : 0;
        ne    = (q == e) ? cq : ne;
    }
    const int brow = by * 320;
    if (brow >= ne) return;
    const int d0 = bx * 128;
    const int kbeg = ks * (IDIM / 2);
    const int tid = threadIdx.x;

    const int wv = tid >> 6, ln = tid & 63;
    const int wm = wv >> 1, wn = wv & 1;
    const int lr = ln & 15, lk = ln >> 4;
    const int col = tid >> 2, bp = tid & 3;

    const unsigned short* aptr[5];
    #pragma unroll
    for (int mf = 0; mf < 5; ++mf) {
        int rg = brow + wm * 80 + mf * 16 + lr;
        int rc = (rg < ne) ? rg : 0;
        aptr[mf] = act + (size_t)(roff + rc) * IDIM + kbeg + lk * 8;
    }
    const float* bsrc = w2 + ((size_t)e * HDIM + d0 + col) * IDIM + kbeg + bp * 8;

    int cfrag[4];
    cfrag[0] = wn * 64;      cfrag[1] = wn * 64 + 16;
    cfrag[2] = wn * 64 + 32; cfrag[3] = wn * 64 + 48;

    short8 aE[5], aO[5];
    f32x4 bS0[2], bS1[2], bS2[2], bS3[2];
    f32x4  acc[5][4] = {};

    constexpr int NT = 32;   // (IDIM/2) / 32

    #pragma unroll
    for (int mf = 0; mf < 5; ++mf) aE[mf] = *(const short8*)(aptr[mf]);
    {
        f32x4 p0 = *(const f32x4*)(bsrc);
        f32x4 p1 = *(const f32x4*)(bsrc + 4);
        *(short8*)(&lB[0][col * 80 + bp * 16]) = cvt8v(p0, p1);
    }
    bS1[0] = *(const f32x4*)(bsrc + 32);  bS1[1] = *(const f32x4*)(bsrc + 36);
    bS2[0] = *(const f32x4*)(bsrc + 64);  bS2[1] = *(const f32x4*)(bsrc + 68);
    asm volatile("s_waitcnt lgkmcnt(0)" ::: "memory");
    __builtin_amdgcn_s_barrier();

#define GSTEP(T_, AU, AP, SPUB, SISS)                                                    \
    {                                                                                    \
        const int t_ = (T_);                                                             \
        if (t_ + 1 < NT) {                                                               \
            _Pragma("unroll")                                                            \
            for (int mf = 0; mf < 5; ++mf)                                               \
                AP[mf] = *(const short8*)(aptr[mf] + (t_ + 1) * 32);                     \
        }                                                                                \
        if (t_ + 3 < NT) {                                                               \
            SISS[0] = *(const f32x4*)(bsrc + (t_ + 3) * 32);                             \
            SISS[1] = *(const f32x4*)(bsrc + (t_ + 3) * 32 + 4);                         \
        }                                                                                \
        __builtin_amdgcn_sched_barrier(0);                                               \
        if (t_ + 1 < NT)                                                                 \
            *(short8*)(&lB[(t_ + 1) & 1][col * 80 + bp * 16]) = cvt8v(SPUB[0], SPUB[1]); \
        short8 bfr[4];                                                                   \
        _Pragma("unroll")                                                                \
        for (int n = 0; n < 4; ++n)                                                      \
            bfr[n] = *(const short8*)(&lB[t_ & 1][(cfrag[n] + lr) * 80 + lk * 16]);      \
        _Pragma("unroll")                                                                \
        for (int mf = 0; mf < 5; ++mf)                                                   \
            _Pragma("unroll")                                                            \
            for (int n = 0; n < 4; ++n)                                                  \
                acc[mf][n] = __builtin_amdgcn_mfma_f32_16x16x32_bf16(                    \
                    AU[mf], bfr[n], acc[mf][n], 0, 0, 0);                                \
        asm volatile("s_waitcnt lgkmcnt(0)" ::: "memory");                               \
        __builtin_amdgcn_s_barrier();                                                    \
    }

    for (int t4 = 0; t4 < NT / 4; ++t4) {
        const int tb = t4 * 4;
        GSTEP(tb + 0, aE, aO, bS1, bS3)
        GSTEP(tb + 1, aO, aE, bS2, bS0)
        GSTEP(tb + 2, aE, aO, bS3, bS1)
        GSTEP(tb + 3, aO, aE, bS0, bS2)
    }
#undef GSTEP

    unsigned short* yb = ks ? ybufB : ybufA;
    #pragma unroll
    for (int mf = 0; mf < 5; ++mf) {
        #pragma unroll
        for (int r = 0; r < 4; ++r) {
            const int rg = brow + wm * 80 + mf * 16 + lk * 4 + r;
            if (rg >= ne) continue;
            unsigned short* yrow = yb + (size_t)(roff + rg) * HDIM;
            #pragma unroll
            for (int n = 0; n < 4; ++n) {
                const int d = d0 + cfrag[n] + lr;
                float v = acc[mf][n][r];
                if (ks == 0) v += b2[(size_t)e * HDIM + d];
                yrow[d] = f2bf(v);
            }
        }
    }
}

// ---------------- combine: out = x + sum_k gate_k * (ybufA+ybufB)[row_k] ----------------
__global__ __launch_bounds__(256) void k_comb(
    const float* __restrict__ x,
    const unsigned short* __restrict__ ybufA, const unsigned short* __restrict__ ybufB,
    const int* __restrict__ rowidx, const float* __restrict__ gate_mk,
    float* __restrict__ out)
{
    __shared__ int   rws[TOPK];
    __shared__ float gws[TOPK];
    const int m = blockIdx.x;
    const int tid = threadIdx.x;
    if (tid < TOPK) {
        rws[tid] = rowidx[m * TOPK + tid];
        gws[tid] = gate_mk[m * TOPK + tid];
    }
    __syncthreads();
    const int d = tid * 8;
    float4 o0 = ((const float4*)(x + (size_t)m * HDIM + d))[0];
    float4 o1 = ((const float4*)(x + (size_t)m * HDIM + d))[1];
    #pragma unroll
    for (int k = 0; k < TOPK; ++k) {
        const float g = gws[k];
        short8 ya = *(const short8*)(ybufA + (size_t)rws[k] * HDIM + d);
        short8 yb = *(const short8*)(ybufB + (size_t)rws[k] * HDIM + d);
        float yv[8];
        #pragma unroll
        for (int j = 0; j < 8; ++j) {
            unsigned ua = ((unsigned)(unsigned short)ya[j]) << 16;
            unsigned ub = ((unsigned)(unsigned short)yb[j]) << 16;
            yv[j] = __builtin_bit_cast(float, ua) + __builtin_bit_cast(float, ub);
        }
        o0.x += g * yv[0]; o0.y += g * yv[1]; o0.z += g * yv[2]; o0.w += g * yv[3];
        o1.x += g * yv[4]; o1.y += g * yv[5]; o1.z += g * yv[6]; o1.w += g * yv[7];
    }
    ((float4*)(out + (size_t)m * HDIM + d))[0] = o0;
    ((float4*)(out + (size_t)m * HDIM + d))[1] = o1;
}

extern "C" void kernel_launch(void* const* d_in, const int* in_sizes, int n_in,
                              void* d_out, int out_size, void* d_ws, size_t ws_size,
                              hipStream_t stream) {
    const float* x      = (const float*)d_in[0];
    const float* norm_w = (const float*)d_in[1];
    const float* gate_w = (const float*)d_in[2];
    const float* gate_b = (const float*)d_in[3];
    const float* w1     = (const float*)d_in[4];
    const float* b1     = (const float*)d_in[5];
    const float* w2     = (const float*)d_in[6];
    const float* b2     = (const float*)d_in[7];
    float* out = (float*)d_out;

    char* ws = (char*)d_ws;
    size_t off = 0;
    unsigned short* t_bf  = (unsigned short*)(ws + off); off += (size_t)MTOK * HDIM * 2;  // 4 MB
    unsigned short* actb  = (unsigned short*)(ws + off); off += (size_t)NA * IDIM * 2;    // 16.8 MB
    unsigned short* ybufA = (unsigned short*)(ws + off); off += (size_t)NA * HDIM * 2;    // 16.8 MB
    unsigned short* ybufB = (unsigned short*)(ws + off); off += (size_t)NA * HDIM * 2;    // 16.8 MB
    int*   counts   = (int*)(ws + off);   off += 256;
    int*   idx_of   = (int*)(ws + off);   off += (size_t)NA * 4;
    int*   slot_of  = (int*)(ws + off);   off += (size_t)NA * 4;
    float* gate_mk  = (float*)(ws + off); off += (size_t)NA * 4;
    int*   token_of = (int*)(ws + off);   off += (size_t)NA * 4;
    int*   rowidx   = (int*)(ws + off);   off += (size_t)NA * 4;

    (void)hipMemsetAsync(counts, 0, 256, stream);
    k_router<<<MTOK, 256, 0, stream>>>(x, norm_w, gate_w, gate_b, t_bf,
                                       counts, idx_of, slot_of, gate_mk);
    k_remap<<<NA / 256, 256, 0, stream>>>(idx_of, slot_of, counts,
                                          token_of, rowidx);
    // 1D grids, XCD-expert pinning: xcd = bid & 7 owns experts {2*xcd, 2*xcd+1}
    k_gemm1<<<1024, 512, 0, stream>>>(t_bf, w1, b1, counts, token_of, actb);
    k_gemm2<<<1024, 512, 0, stream>>>(actb, w2, b2, counts, token_of, ybufA, ybufB);
    k_comb<<<MTOK, 256, 0, stream>>>(x, ybufA, ybufB, rowidx, gate_mk, out);
}